// Round 1
// baseline (556.215 us; speedup 1.0000x reference)
//
#include <hip/hip_runtime.h>

#define B_   8
#define CIN  256
#define T_   4096
#define CO   256
#define O4   1024
#define KK   512
#define NCH  128   // chunks along T
#define CL   32    // chunk length

// ws layout (float offsets)
#define OFF_XS   0          // [8][256][4096]
#define OFF_WT   8388608    // [512][1024]
#define OFF_F    8912896    // [8][4096][256]
#define OFF_IZ   17301504
#define OFF_O    25690112
#define OFF_A    34078720   // [8][128][256]
#define OFF_B    34340864
#define OFF_C    34603008
// total 34,865,152 floats = 139.5 MB

__device__ __forceinline__ float fsig(float x)  { return 1.0f / (1.0f + __expf(-x)); }
__device__ __forceinline__ float ftanh(float x) { return 2.0f / (1.0f + __expf(-2.0f * x)) - 1.0f; }

// xs[b,i,t] = x[b,i,t-1], xs[b,i,0] = 0
__global__ void shift_x_kernel(const float* __restrict__ x, float* __restrict__ xs) {
    int tid = blockIdx.x * 256 + threadIdx.x;
    int t = tid & (T_ - 1);
    xs[tid] = (t == 0) ? 0.0f : x[tid - 1];
}

// W[o,i,j] -> Wt[k=j*256+i][r=c*4+g], o = g*256+c
__global__ void repack_w_kernel(const float* __restrict__ W, float* __restrict__ Wt) {
    int tid = blockIdx.x * 256 + threadIdx.x;     // 524288
    int o   = tid >> 9;
    int rem = tid & 511;
    int i = rem >> 1, j = rem & 1;
    int g = o >> 8,  c = o & 255;
    Wt[(j * 256 + i) * 1024 + (c * 4 + g)] = W[tid];
}

// C[r, n] = sum_k Wt[k][r] * Xmat[k][n],  n = b*T + t, k = j*256+i
// Xmat[k][n] = (j==0 ? xs : x)[b, i, t]
// fused epilogue: bias + activations, writes f, i*z, o as [b][t][c]
__launch_bounds__(256, 4)
__global__ void gemm_gates_kernel(const float* __restrict__ x,
                                  const float* __restrict__ xs,
                                  const float* __restrict__ Wt,
                                  const float* __restrict__ bias,
                                  float* __restrict__ fw,
                                  float* __restrict__ izw,
                                  float* __restrict__ ow)
{
    const int tid = threadIdx.x;
    const int tx = tid & 15, ty = tid >> 4;
    const int n0 = blockIdx.x * 128;
    const int bb = n0 >> 12;
    const int t0 = n0 & (T_ - 1);
    const int r0 = blockIdx.y * 128;

    __shared__ float As[16][132];
    __shared__ float Bs[16][132];

    float acc[8][8];
#pragma unroll
    for (int v = 0; v < 8; v++)
#pragma unroll
        for (int u = 0; u < 8; u++) acc[v][u] = 0.0f;

    for (int kk = 0; kk < KK; kk += 16) {
#pragma unroll
        for (int h = 0; h < 2; h++) {
            int qq  = tid * 4 + h * 1024;
            int row = qq >> 7, col = qq & 127;
            *(float4*)&As[row][col] = *(const float4*)&Wt[(size_t)(kk + row) * 1024 + r0 + col];
            int gk = kk + row;
            const float* src = (gk < 256 ? xs : x)
                             + ((size_t)(bb * 256 + (gk & 255))) * T_ + t0 + col;
            *(float4*)&Bs[row][col] = *(const float4*)src;
        }
        __syncthreads();
#pragma unroll
        for (int k = 0; k < 16; k++) {
            float a[8], bv[8];
            *(float4*)&a[0] = *(float4*)&As[k][ty * 8];
            *(float4*)&a[4] = *(float4*)&As[k][ty * 8 + 4];
#pragma unroll
            for (int u = 0; u < 8; u++) bv[u] = Bs[k][tx + 16 * u];
#pragma unroll
            for (int v = 0; v < 8; v++)
#pragma unroll
                for (int u = 0; u < 8; u++)
                    acc[v][u] = fmaf(a[v], bv[u], acc[v][u]);
        }
        __syncthreads();
    }

    // thread rows r = r0 + ty*8 + v : 2 channels x 4 gates (g = v&3, order Z,F,O,I)
    const int ch0 = (r0 + ty * 8) >> 2;
#pragma unroll
    for (int p = 0; p < 2; p++) {
        int c = ch0 + p;
        float bz = bias[c], bf = bias[256 + c], bo = bias[512 + c], bi = bias[768 + c];
#pragma unroll
        for (int u = 0; u < 8; u++) {
            int t = t0 + tx + 16 * u;
            float zv = ftanh(acc[4 * p + 0][u] + bz);
            float fv = fsig (acc[4 * p + 1][u] + bf);
            float ov = fsig (acc[4 * p + 2][u] + bo);
            float iv = fsig (acc[4 * p + 3][u] + bi);
            size_t idx = ((size_t)(bb * T_ + t)) * CO + c;
            fw[idx]  = fv;
            izw[idx] = iv * zv;
            ow[idx]  = ov;
        }
    }
}

// Phase 1: per-chunk affine composition (A = prod f, B = c_end with c_in=0)
__global__ void scan_phase1(const float* __restrict__ fw, const float* __restrict__ izw,
                            float* __restrict__ Aw, float* __restrict__ Bw)
{
    int b = blockIdx.y, ch = blockIdx.x, c = threadIdx.x;
    size_t base = ((size_t)(b * T_ + ch * CL)) * CO + c;
    float A = 1.0f, Bv = 0.0f;
#pragma unroll 4
    for (int tt = 0; tt < CL; tt++) {
        float f  = fw[base + (size_t)tt * CO];
        float iz = izw[base + (size_t)tt * CO];
        Bv = fmaf(f, Bv, iz);
        A *= f;
    }
    size_t idx = ((size_t)(b * NCH + ch)) * CO + c;
    Aw[idx] = A;
    Bw[idx] = Bv;
}

// Phase 2: exclusive scan over chunk summaries -> carry-in per chunk
__global__ void scan_phase2(const float* __restrict__ Aw, const float* __restrict__ Bw,
                            float* __restrict__ cw)
{
    int b = blockIdx.x, c = threadIdx.x;
    float carry = 0.0f;
    for (int ch = 0; ch < NCH; ch++) {
        size_t idx = ((size_t)(b * NCH + ch)) * CO + c;
        cw[idx] = carry;
        carry = fmaf(Aw[idx], carry, Bw[idx]);
    }
}

// Phase 3: replay recurrence with carry, h = o*c, transpose [t][c] -> out[b][c][t] via LDS
__global__ void scan_phase3(const float* __restrict__ fw, const float* __restrict__ izw,
                            const float* __restrict__ ow, const float* __restrict__ cw,
                            float* __restrict__ out)
{
    __shared__ float hbuf[CL][257];
    int b = blockIdx.y, ch = blockIdx.x, c = threadIdx.x;
    float cs = cw[((size_t)(b * NCH + ch)) * CO + c];
    size_t base = ((size_t)(b * T_ + ch * CL)) * CO + c;
#pragma unroll 4
    for (int tt = 0; tt < CL; tt++) {
        float f  = fw[base + (size_t)tt * CO];
        float iz = izw[base + (size_t)tt * CO];
        float o  = ow[base + (size_t)tt * CO];
        cs = fmaf(f, cs, iz);
        hbuf[tt][c] = o * cs;
    }
    __syncthreads();
    int tt = threadIdx.x & 31;
    int cr = threadIdx.x >> 5;  // 0..7
#pragma unroll
    for (int w = 0; w < 32; w++) {
        int cc = cr + w * 8;
        out[((size_t)(b * CO + cc)) * T_ + ch * CL + tt] = hbuf[tt][cc];
    }
}

extern "C" void kernel_launch(void* const* d_in, const int* in_sizes, int n_in,
                              void* d_out, int out_size, void* d_ws, size_t ws_size,
                              hipStream_t stream) {
    const float* x    = (const float*)d_in[0];
    const float* W    = (const float*)d_in[1];
    const float* bias = (const float*)d_in[2];
    float* out = (float*)d_out;
    float* ws  = (float*)d_ws;

    float* xs  = ws + OFF_XS;
    float* Wt  = ws + OFF_WT;
    float* fw  = ws + OFF_F;
    float* izw = ws + OFF_IZ;
    float* ow  = ws + OFF_O;
    float* Aw  = ws + OFF_A;
    float* Bw  = ws + OFF_B;
    float* cw  = ws + OFF_C;

    shift_x_kernel<<<(B_ * CIN * T_) / 256, 256, 0, stream>>>(x, xs);
    repack_w_kernel<<<(O4 * CIN * 2) / 256, 256, 0, stream>>>(W, Wt);
    gemm_gates_kernel<<<dim3((B_ * T_) / 128, O4 / 128), 256, 0, stream>>>(
        x, xs, Wt, bias, fw, izw, ow);
    scan_phase1<<<dim3(NCH, B_), CO, 0, stream>>>(fw, izw, Aw, Bw);
    scan_phase2<<<B_, CO, 0, stream>>>(Aw, Bw, cw);
    scan_phase3<<<dim3(NCH, B_), CO, 0, stream>>>(fw, izw, ow, cw, out);
}

// Round 2
// 289.748 us; speedup vs baseline: 1.9196x; 1.9196x over previous
//
#include <hip/hip_runtime.h>

#define B_   8
#define CIN  256
#define T_   4096
#define CO   256
#define O4   1024
#define KK   512
#define NN   32768   // B_*T_
#define NCH  128     // chunks along T
#define CL   32      // chunk length

// ws layout (float offsets). ushort arrays count 2 ushorts per float slot.
#define OFF_XHI  0           // ushort [32768][512]
#define OFF_XLO  8388608     // ushort [32768][512]
#define OFF_WHI  16777216    // ushort [1024][512]
#define OFF_WLO  17039360
#define OFF_F    17301504    // float [8][4096][256]
#define OFF_IZ   25690112
#define OFF_O    34078720
#define OFF_A    42467328    // float [8][128][256]
#define OFF_B    42729472
#define OFF_C    42991616
// total 43,253,760 floats = 173 MB

typedef __attribute__((ext_vector_type(8))) short short8;
typedef __attribute__((ext_vector_type(8))) unsigned short ushort8v;
typedef __attribute__((ext_vector_type(4))) float floatx4;

__device__ __forceinline__ float fsig(float x)  { return 1.0f / (1.0f + __expf(-x)); }
__device__ __forceinline__ float ftanh(float x) { return 2.0f / (1.0f + __expf(-2.0f * x)) - 1.0f; }

__device__ __forceinline__ unsigned short bf16_rne(float v) {
    unsigned u = __float_as_uint(v);
    unsigned r = (u + 0x7fffu + ((u >> 16) & 1u)) >> 16;
    return (unsigned short)r;
}
__device__ __forceinline__ void split_bf16(float v, unsigned short& hi, unsigned short& lo) {
    hi = bf16_rne(v);
    float hf = __uint_as_float(((unsigned)hi) << 16);
    lo = bf16_rne(v - hf);
}

// W[o=g*256+c][i][j] -> Wa[r=c*4+g][k=j*256+i], split hi/lo bf16
__global__ void convert_w_kernel(const float* __restrict__ W,
                                 unsigned short* __restrict__ Whi,
                                 unsigned short* __restrict__ Wlo) {
    int tid = blockIdx.x * 256 + threadIdx.x;   // 1024*512
    int r = tid >> 9, k = tid & 511;
    int g = r & 3, c = r >> 2;
    int j = k >> 8, i = k & 255;
    float v = W[((size_t)((g << 8) + c)) * 512 + i * 2 + j];
    unsigned short hi, lo;
    split_bf16(v, hi, lo);
    Whi[tid] = hi;
    Wlo[tid] = lo;
}

// x[b][c][t] -> Xb[n=b*4096+t][k], k<256: tap j=0 (x[t-1], ch k), k>=256: tap j=1 (x[t], ch k-256)
// split hi/lo bf16; transpose via LDS tile.
__global__ void convert_x_kernel(const float* __restrict__ x,
                                 unsigned short* __restrict__ Xhi,
                                 unsigned short* __restrict__ Xlo) {
    __shared__ float tile[64][65];
    int b  = blockIdx.z;
    int c0 = blockIdx.y * 64;
    int t0 = blockIdx.x * 64;
    int tid = threadIdx.x;

    // read coalesced along t
    {
        int j = tid & 63, r4 = tid >> 6;   // 4 rows per pass
#pragma unroll
        for (int p = 0; p < 16; p++) {
            int i = p * 4 + r4;
            tile[i][j] = x[((size_t)(b * 256 + c0 + i)) * T_ + t0 + j];
        }
    }
    __syncthreads();
    // write coalesced along k (= channel direction)
    {
        int i = tid & 63, jj = tid >> 6;
#pragma unroll
        for (int p = 0; p < 16; p++) {
            int j = jj * 16 + p;
            float v = tile[i][j];
            unsigned short hi, lo;
            split_bf16(v, hi, lo);
            size_t n = (size_t)b * T_ + t0 + j;
            // unshifted: tap j=1, k = 256 + c
            Xhi[n * 512 + 256 + c0 + i] = hi;
            Xlo[n * 512 + 256 + c0 + i] = lo;
            // shifted: contributes to t+1 at tap 0, k = c
            if (t0 + j + 1 < T_) {
                Xhi[(n + 1) * 512 + c0 + i] = hi;
                Xlo[(n + 1) * 512 + c0 + i] = lo;
            }
            if (t0 == 0 && jj == 0 && p == 0) {
                Xhi[((size_t)b * T_) * 512 + c0 + i] = 0;
                Xlo[((size_t)b * T_) * 512 + c0 + i] = 0;
            }
        }
    }
}

// C[r=1024][n=32768] = Wa · Xb^T via split-bf16 MFMA (3 products, fp32 accum).
// 128x128 tile, BK=32, 4 waves each 64x64 (4x4 of 16x16x32).
// Epilogue: bias + activations -> fw, izw, ow in [b][t][c].
__launch_bounds__(256, 2)
__global__ void gemm_mfma_kernel(const unsigned short* __restrict__ Xhi,
                                 const unsigned short* __restrict__ Xlo,
                                 const unsigned short* __restrict__ Whi,
                                 const unsigned short* __restrict__ Wlo,
                                 const float* __restrict__ bias,
                                 float* __restrict__ fw,
                                 float* __restrict__ izw,
                                 float* __restrict__ ow)
{
    __shared__ unsigned short As[2][128][40];  // pad 40: rows 80B -> 16B-aligned, 2-way banks (free)
    __shared__ unsigned short Bs[2][128][40];

    const int tid  = threadIdx.x;
    const int wave = tid >> 6, lane = tid & 63;
    const int q = lane >> 4, mr = lane & 15;
    const int r0 = blockIdx.y * 128;
    const int n0 = blockIdx.x * 128;
    const int m_base = (wave & 1) * 64;
    const int n_base = (wave >> 1) * 64;
    const int lrow = tid >> 1, lchunk = (tid & 1) * 16;

    floatx4 acc[4][4];
#pragma unroll
    for (int v = 0; v < 4; v++)
#pragma unroll
        for (int u = 0; u < 4; u++) acc[v][u] = (floatx4){0.f, 0.f, 0.f, 0.f};

    const unsigned short* wh = Whi + (size_t)(r0 + lrow) * 512 + lchunk;
    const unsigned short* wl = Wlo + (size_t)(r0 + lrow) * 512 + lchunk;
    const unsigned short* xh = Xhi + (size_t)(n0 + lrow) * 512 + lchunk;
    const unsigned short* xl = Xlo + (size_t)(n0 + lrow) * 512 + lchunk;

    for (int kk = 0; kk < KK; kk += 32) {
        __syncthreads();
        *(ushort8v*)&As[0][lrow][lchunk]     = *(const ushort8v*)(wh + kk);
        *(ushort8v*)&As[0][lrow][lchunk + 8] = *(const ushort8v*)(wh + kk + 8);
        *(ushort8v*)&As[1][lrow][lchunk]     = *(const ushort8v*)(wl + kk);
        *(ushort8v*)&As[1][lrow][lchunk + 8] = *(const ushort8v*)(wl + kk + 8);
        *(ushort8v*)&Bs[0][lrow][lchunk]     = *(const ushort8v*)(xh + kk);
        *(ushort8v*)&Bs[0][lrow][lchunk + 8] = *(const ushort8v*)(xh + kk + 8);
        *(ushort8v*)&Bs[1][lrow][lchunk]     = *(const ushort8v*)(xl + kk);
        *(ushort8v*)&Bs[1][lrow][lchunk + 8] = *(const ushort8v*)(xl + kk + 8);
        __syncthreads();

        short8 ah[4], al[4], bh[4], bl[4];
#pragma unroll
        for (int v = 0; v < 4; v++) {
            ah[v] = *(const short8*)&As[0][m_base + v * 16 + mr][q * 8];
            al[v] = *(const short8*)&As[1][m_base + v * 16 + mr][q * 8];
        }
#pragma unroll
        for (int u = 0; u < 4; u++) {
            bh[u] = *(const short8*)&Bs[0][n_base + u * 16 + mr][q * 8];
            bl[u] = *(const short8*)&Bs[1][n_base + u * 16 + mr][q * 8];
        }
#pragma unroll
        for (int v = 0; v < 4; v++)
#pragma unroll
            for (int u = 0; u < 4; u++)
                acc[v][u] = __builtin_amdgcn_mfma_f32_16x16x32_bf16(ah[v], bh[u], acc[v][u], 0, 0, 0);
#pragma unroll
        for (int v = 0; v < 4; v++)
#pragma unroll
            for (int u = 0; u < 4; u++)
                acc[v][u] = __builtin_amdgcn_mfma_f32_16x16x32_bf16(ah[v], bl[u], acc[v][u], 0, 0, 0);
#pragma unroll
        for (int v = 0; v < 4; v++)
#pragma unroll
            for (int u = 0; u < 4; u++)
                acc[v][u] = __builtin_amdgcn_mfma_f32_16x16x32_bf16(al[v], bh[u], acc[v][u], 0, 0, 0);
    }

    // Epilogue. D row R = r0+m_base+v*16 + q*4 + g, col N = n0+n_base+u*16+mr.
    // R = c*4+g with c = (r0+m_base)/4 + 4v + q ; regs 0..3 = gates Z,F,O,I of channel c.
    const int bb = n0 >> 12;
    const int t_base = (n0 & (T_ - 1)) + n_base + mr;
#pragma unroll
    for (int v = 0; v < 4; v++) {
        int c = ((r0 + m_base) >> 2) + v * 4 + q;
        float bz = bias[c], bf_ = bias[256 + c], bo = bias[512 + c], bi = bias[768 + c];
#pragma unroll
        for (int u = 0; u < 4; u++) {
            int t = t_base + u * 16;
            float zv = ftanh(acc[v][u][0] + bz);
            float fv = fsig (acc[v][u][1] + bf_);
            float ov = fsig (acc[v][u][2] + bo);
            float iv = fsig (acc[v][u][3] + bi);
            size_t idx = ((size_t)(bb * T_ + t)) * CO + c;
            fw[idx]  = fv;
            izw[idx] = iv * zv;
            ow[idx]  = ov;
        }
    }
}

// Phase 1: per-chunk affine composition (A = prod f, B = c_end with c_in=0)
__global__ void scan_phase1(const float* __restrict__ fw, const float* __restrict__ izw,
                            float* __restrict__ Aw, float* __restrict__ Bw)
{
    int b = blockIdx.y, ch = blockIdx.x, c = threadIdx.x;
    size_t base = ((size_t)(b * T_ + ch * CL)) * CO + c;
    float A = 1.0f, Bv = 0.0f;
#pragma unroll 4
    for (int tt = 0; tt < CL; tt++) {
        float f  = fw[base + (size_t)tt * CO];
        float iz = izw[base + (size_t)tt * CO];
        Bv = fmaf(f, Bv, iz);
        A *= f;
    }
    size_t idx = ((size_t)(b * NCH + ch)) * CO + c;
    Aw[idx] = A;
    Bw[idx] = Bv;
}

// Phase 2: exclusive scan over chunk summaries -> carry-in per chunk
__global__ void scan_phase2(const float* __restrict__ Aw, const float* __restrict__ Bw,
                            float* __restrict__ cw)
{
    int b = blockIdx.x, c = threadIdx.x;
    float carry = 0.0f;
    for (int ch = 0; ch < NCH; ch++) {
        size_t idx = ((size_t)(b * NCH + ch)) * CO + c;
        cw[idx] = carry;
        carry = fmaf(Aw[idx], carry, Bw[idx]);
    }
}

// Phase 3: replay recurrence with carry, h = o*c, transpose [t][c] -> out[b][c][t] via LDS
__global__ void scan_phase3(const float* __restrict__ fw, const float* __restrict__ izw,
                            const float* __restrict__ ow, const float* __restrict__ cw,
                            float* __restrict__ out)
{
    __shared__ float hbuf[CL][257];
    int b = blockIdx.y, ch = blockIdx.x, c = threadIdx.x;
    float cs = cw[((size_t)(b * NCH + ch)) * CO + c];
    size_t base = ((size_t)(b * T_ + ch * CL)) * CO + c;
#pragma unroll 4
    for (int tt = 0; tt < CL; tt++) {
        float f  = fw[base + (size_t)tt * CO];
        float iz = izw[base + (size_t)tt * CO];
        float o  = ow[base + (size_t)tt * CO];
        cs = fmaf(f, cs, iz);
        hbuf[tt][c] = o * cs;
    }
    __syncthreads();
    int tt = threadIdx.x & 31;
    int cr = threadIdx.x >> 5;  // 0..7
#pragma unroll
    for (int w = 0; w < 32; w++) {
        int cc = cr + w * 8;
        out[((size_t)(b * CO + cc)) * T_ + ch * CL + tt] = hbuf[tt][cc];
    }
}

extern "C" void kernel_launch(void* const* d_in, const int* in_sizes, int n_in,
                              void* d_out, int out_size, void* d_ws, size_t ws_size,
                              hipStream_t stream) {
    const float* x    = (const float*)d_in[0];
    const float* W    = (const float*)d_in[1];
    const float* bias = (const float*)d_in[2];
    float* out = (float*)d_out;
    float* ws  = (float*)d_ws;

    unsigned short* Xhi = (unsigned short*)(ws + OFF_XHI);
    unsigned short* Xlo = (unsigned short*)(ws + OFF_XLO);
    unsigned short* Whi = (unsigned short*)(ws + OFF_WHI);
    unsigned short* Wlo = (unsigned short*)(ws + OFF_WLO);
    float* fw  = ws + OFF_F;
    float* izw = ws + OFF_IZ;
    float* ow  = ws + OFF_O;
    float* Aw  = ws + OFF_A;
    float* Bw  = ws + OFF_B;
    float* cw  = ws + OFF_C;

    convert_w_kernel<<<(O4 * KK) / 256, 256, 0, stream>>>(W, Whi, Wlo);
    convert_x_kernel<<<dim3(T_ / 64, CIN / 64, B_), 256, 0, stream>>>(x, Xhi, Xlo);
    gemm_mfma_kernel<<<dim3(NN / 128, O4 / 128), 256, 0, stream>>>(
        Xhi, Xlo, Whi, Wlo, bias, fw, izw, ow);
    scan_phase1<<<dim3(NCH, B_), CO, 0, stream>>>(fw, izw, Aw, Bw);
    scan_phase2<<<B_, CO, 0, stream>>>(Aw, Bw, cw);
    scan_phase3<<<dim3(NCH, B_), CO, 0, stream>>>(fw, izw, ow, cw, out);
}

// Round 3
// 254.281 us; speedup vs baseline: 2.1874x; 1.1395x over previous
//
#include <hip/hip_runtime.h>

#define B_   8
#define CIN  256
#define T_   4096
#define CO   256
#define O4   1024
#define KK   512
#define NN   32768   // B_*T_
#define NCH  128     // chunks along T
#define CL   32      // chunk length

// ws layout (float offsets)
#define OFF_XHI  0           // ushort [32768][256]  (16 MB)
#define OFF_XLO  4194304
#define OFF_WHI  8388608     // ushort [1024][512]
#define OFF_WLO  8650752
#define OFF_F    8912896     // float [8][4096][256]
#define OFF_IZ   17301504
#define OFF_O    25690112
#define OFF_A    34078720    // float [8][128][256]
#define OFF_B    34340864
#define OFF_C    34603008
// total 34,865,152 floats = 139.5 MB

typedef __attribute__((ext_vector_type(8))) short short8;
typedef __attribute__((ext_vector_type(8))) unsigned short ushort8v;
typedef __attribute__((ext_vector_type(4))) float floatx4;

__device__ __forceinline__ float fsig(float x)  { return 1.0f / (1.0f + __expf(-x)); }
__device__ __forceinline__ float ftanh(float x) { return 2.0f / (1.0f + __expf(-2.0f * x)) - 1.0f; }

__device__ __forceinline__ unsigned short bf16_rne(float v) {
    unsigned u = __float_as_uint(v);
    unsigned r = (u + 0x7fffu + ((u >> 16) & 1u)) >> 16;
    return (unsigned short)r;
}
__device__ __forceinline__ void split_bf16(float v, unsigned short& hi, unsigned short& lo) {
    hi = bf16_rne(v);
    float hf = __uint_as_float(((unsigned)hi) << 16);
    lo = bf16_rne(v - hf);
}

// W[o=g*256+c][i][j] -> Wa[r=c*4+g][k=j*256+i], split hi/lo bf16
__global__ void convert_w_kernel(const float* __restrict__ W,
                                 unsigned short* __restrict__ Whi,
                                 unsigned short* __restrict__ Wlo) {
    int tid = blockIdx.x * 256 + threadIdx.x;   // 1024*512
    int r = tid >> 9, k = tid & 511;
    int g = r & 3, c = r >> 2;
    int j = k >> 8, i = k & 255;
    float v = W[((size_t)((g << 8) + c)) * 512 + i * 2 + j];
    unsigned short hi, lo;
    split_bf16(v, hi, lo);
    Whi[tid] = hi;
    Wlo[tid] = lo;
}

// x[b][c][t] -> Xt[b][t][c] bf16 hi/lo (deduplicated; taps handled in GEMM staging)
__global__ void convert_x_kernel(const float* __restrict__ x,
                                 unsigned short* __restrict__ Xhi,
                                 unsigned short* __restrict__ Xlo) {
    __shared__ float tile[64][65];
    int b  = blockIdx.z;
    int c0 = blockIdx.y * 64;
    int t0 = blockIdx.x * 64;
    int tid = threadIdx.x;

    {   // read coalesced along t
        int j = tid & 63, r4 = tid >> 6;
#pragma unroll
        for (int p = 0; p < 16; p++) {
            int i = p * 4 + r4;
            tile[i][j] = x[((size_t)(b * 256 + c0 + i)) * T_ + t0 + j];
        }
    }
    __syncthreads();
    {   // write coalesced along c
        int i = tid & 63, jj = tid >> 6;
#pragma unroll
        for (int p = 0; p < 16; p++) {
            int t = jj * 16 + p;
            float v = tile[i][t];
            unsigned short hi, lo;
            split_bf16(v, hi, lo);
            size_t idx = ((size_t)b * T_ + t0 + t) * 256 + c0 + i;
            Xhi[idx] = hi;
            Xlo[idx] = lo;
        }
    }
}

// C[r=1024][n=32768] = Wa · Xb^T, split-bf16 MFMA (3 products), 128x128 tile, BK=32.
// XOR-granule LDS (64B rows). Epilogue: activations -> LDS [t][c] -> coalesced
// stores of f/iz/o + fused per-chunk scan summaries (Aw,Bw).
__launch_bounds__(256, 3)
__global__ void gemm_mfma_kernel(const unsigned short* __restrict__ Xhi,
                                 const unsigned short* __restrict__ Xlo,
                                 const unsigned short* __restrict__ Whi,
                                 const unsigned short* __restrict__ Wlo,
                                 const float* __restrict__ bias,
                                 float* __restrict__ fw,
                                 float* __restrict__ izw,
                                 float* __restrict__ ow,
                                 float* __restrict__ Aw,
                                 float* __restrict__ Bw)
{
    __shared__ float smem_f[3 * 128 * 33];           // 50,688 B
    unsigned short* smem_us = (unsigned short*)smem_f;
    unsigned short* pA_hi = smem_us;                 // [128][32] each, granule-XOR
    unsigned short* pA_lo = smem_us + 4096;
    unsigned short* pB_hi = smem_us + 8192;
    unsigned short* pB_lo = smem_us + 12288;

    const int tid  = threadIdx.x;
    const int wave = tid >> 6, lane = tid & 63;
    const int q = lane >> 4, mr = lane & 15;
    const int bid = blockIdx.x;
    const int r_blk = bid & 7, n_blk = bid >> 3;
    const int r0 = r_blk * 128;
    const int n0 = n_blk * 128;
    const int bb = n0 >> 12;
    const int t0 = n0 & (T_ - 1);
    const int m_base = (wave & 1) * 64;
    const int n_base = (wave >> 1) * 64;

    // staging indices: thread -> row r, 16-ushort chunk kb
    const int sr = tid >> 1;
    const int kb = (tid & 1) << 4;
    const int g0 = ((kb >> 3) + 0) ^ (sr & 3);
    const int g1 = ((kb >> 3) + 1) ^ (sr & 3);
    const int sA = sr * 32;                           // row base (ushorts)
    const ushort8v zz = {0, 0, 0, 0, 0, 0, 0, 0};

    const unsigned short* whp = Whi + (size_t)(r0 + sr) * 512 + kb;
    const unsigned short* wlp = Wlo + (size_t)(r0 + sr) * 512 + kb;

    floatx4 acc[4][4];
#pragma unroll
    for (int v = 0; v < 4; v++)
#pragma unroll
        for (int u = 0; u < 4; u++) acc[v][u] = (floatx4){0.f, 0.f, 0.f, 0.f};

    const int swq = q ^ (mr & 3);                     // fragment-read granule

    for (int kk = 0; kk < KK; kk += 32) {
        __syncthreads();
        // ---- stage A (Whi/Wlo) ----
        *(ushort8v*)(pA_hi + sA + (g0 << 3)) = *(const ushort8v*)(whp + kk);
        *(ushort8v*)(pA_hi + sA + (g1 << 3)) = *(const ushort8v*)(whp + kk + 8);
        *(ushort8v*)(pA_lo + sA + (g0 << 3)) = *(const ushort8v*)(wlp + kk);
        *(ushort8v*)(pA_lo + sA + (g1 << 3)) = *(const ushort8v*)(wlp + kk + 8);
        // ---- stage B (Xt, tap via t-window shift) ----
        {
            const int tap0 = (kk < 256) ? 1 : 0;      // k<256 -> x[t-1]
            const int t_abs = t0 + sr;
            const bool zer = (tap0 == 1) && (t_abs == 0);
            const size_t t_src = (size_t)(zer ? 0 : (t_abs - tap0));
            const int c_off = (kk & 255) + kb;
            const unsigned short* xh = Xhi + ((size_t)bb * T_ + t_src) * 256 + c_off;
            const unsigned short* xl = Xlo + ((size_t)bb * T_ + t_src) * 256 + c_off;
            ushort8v h0 = *(const ushort8v*)xh;
            ushort8v h1 = *(const ushort8v*)(xh + 8);
            ushort8v l0 = *(const ushort8v*)xl;
            ushort8v l1 = *(const ushort8v*)(xl + 8);
            if (zer) { h0 = zz; h1 = zz; l0 = zz; l1 = zz; }
            *(ushort8v*)(pB_hi + sA + (g0 << 3)) = h0;
            *(ushort8v*)(pB_hi + sA + (g1 << 3)) = h1;
            *(ushort8v*)(pB_lo + sA + (g0 << 3)) = l0;
            *(ushort8v*)(pB_lo + sA + (g1 << 3)) = l1;
        }
        __syncthreads();

        short8 ah[4], al[4], bh[4], bl[4];
#pragma unroll
        for (int v = 0; v < 4; v++) {
            int m = m_base + v * 16 + mr;
            ah[v] = *(const short8*)(pA_hi + m * 32 + (swq << 3));
            al[v] = *(const short8*)(pA_lo + m * 32 + (swq << 3));
        }
#pragma unroll
        for (int u = 0; u < 4; u++) {
            int n = n_base + u * 16 + mr;
            bh[u] = *(const short8*)(pB_hi + n * 32 + (swq << 3));
            bl[u] = *(const short8*)(pB_lo + n * 32 + (swq << 3));
        }
#pragma unroll
        for (int v = 0; v < 4; v++)
#pragma unroll
            for (int u = 0; u < 4; u++)
                acc[v][u] = __builtin_amdgcn_mfma_f32_16x16x32_bf16(ah[v], bh[u], acc[v][u], 0, 0, 0);
#pragma unroll
        for (int v = 0; v < 4; v++)
#pragma unroll
            for (int u = 0; u < 4; u++)
                acc[v][u] = __builtin_amdgcn_mfma_f32_16x16x32_bf16(ah[v], bl[u], acc[v][u], 0, 0, 0);
#pragma unroll
        for (int v = 0; v < 4; v++)
#pragma unroll
            for (int u = 0; u < 4; u++)
                acc[v][u] = __builtin_amdgcn_mfma_f32_16x16x32_bf16(al[v], bh[u], acc[v][u], 0, 0, 0);
    }

    // ---------- epilogue ----------
    float* epf = smem_f;                 // [128][33]
    float* epz = smem_f + 4224;
    float* epo = smem_f + 8448;

    __syncthreads();                     // all fragment reads done
#pragma unroll
    for (int v = 0; v < 4; v++) {
        int cl = (m_base >> 2) + v * 4 + q;          // local channel 0..31
        int c  = (r0 >> 2) + cl;
        float bz = bias[c], bf_ = bias[256 + c], bo = bias[512 + c], bi = bias[768 + c];
#pragma unroll
        for (int u = 0; u < 4; u++) {
            int t_l = n_base + u * 16 + mr;
            float zv = ftanh(acc[v][u][0] + bz);
            float fv = fsig (acc[v][u][1] + bf_);
            float ov = fsig (acc[v][u][2] + bo);
            float iv = fsig (acc[v][u][3] + bi);
            int off = t_l * 33 + cl;
            epf[off] = fv;
            epz[off] = iv * zv;
            epo[off] = ov;
        }
    }
    __syncthreads();

    // coalesced stores: thread -> t_r = tid>>1, 16 consecutive c
    {
        const int t_r = tid >> 1;
        const int cb = (tid & 1) << 4;
        const size_t gbase = ((size_t)bb * T_ + t0 + t_r) * 256 + (r0 >> 2) + cb;
        const int lbase = t_r * 33 + cb;
#pragma unroll
        for (int j4 = 0; j4 < 4; j4++) {
            float4 vf = { epf[lbase + j4 * 4], epf[lbase + j4 * 4 + 1],
                          epf[lbase + j4 * 4 + 2], epf[lbase + j4 * 4 + 3] };
            *(float4*)&fw[gbase + j4 * 4] = vf;
        }
#pragma unroll
        for (int j4 = 0; j4 < 4; j4++) {
            float4 vz = { epz[lbase + j4 * 4], epz[lbase + j4 * 4 + 1],
                          epz[lbase + j4 * 4 + 2], epz[lbase + j4 * 4 + 3] };
            *(float4*)&izw[gbase + j4 * 4] = vz;
        }
#pragma unroll
        for (int j4 = 0; j4 < 4; j4++) {
            float4 vo = { epo[lbase + j4 * 4], epo[lbase + j4 * 4 + 1],
                          epo[lbase + j4 * 4 + 2], epo[lbase + j4 * 4 + 3] };
            *(float4*)&ow[gbase + j4 * 4] = vo;
        }
    }

    // fused scan phase 1: per-chunk (A = prod f, B = affine end) from LDS
    if (tid < 128) {
        const int chunk = tid >> 5, cc = tid & 31;
        float A = 1.0f, Bv = 0.0f;
        int base = (chunk * 32) * 33 + cc;
#pragma unroll 4
        for (int j = 0; j < 32; j++) {
            float f  = epf[base + j * 33];
            float iz = epz[base + j * 33];
            Bv = fmaf(f, Bv, iz);
            A *= f;
        }
        const int chunk_abs = (t0 >> 5) + chunk;
        const size_t aidx = ((size_t)bb * NCH + chunk_abs) * 256 + (r0 >> 2) + cc;
        Aw[aidx] = A;
        Bw[aidx] = Bv;
    }
}

// Phase 2: exclusive scan over chunk summaries -> carry-in per chunk
__global__ void scan_phase2(const float* __restrict__ Aw, const float* __restrict__ Bw,
                            float* __restrict__ cw)
{
    int b = blockIdx.x, c = threadIdx.x;
    float carry = 0.0f;
    for (int ch = 0; ch < NCH; ch++) {
        size_t idx = ((size_t)(b * NCH + ch)) * CO + c;
        cw[idx] = carry;
        carry = fmaf(Aw[idx], carry, Bw[idx]);
    }
}

// Phase 3: replay recurrence with carry, h = o*c, transpose [t][c] -> out[b][c][t]
__global__ void scan_phase3(const float* __restrict__ fw, const float* __restrict__ izw,
                            const float* __restrict__ ow, const float* __restrict__ cw,
                            float* __restrict__ out)
{
    __shared__ float hbuf[CL][257];
    int b = blockIdx.y, ch = blockIdx.x, c = threadIdx.x;
    float cs = cw[((size_t)(b * NCH + ch)) * CO + c];
    size_t base = ((size_t)(b * T_ + ch * CL)) * CO + c;
#pragma unroll 4
    for (int tt = 0; tt < CL; tt++) {
        float f  = fw[base + (size_t)tt * CO];
        float iz = izw[base + (size_t)tt * CO];
        float o  = ow[base + (size_t)tt * CO];
        cs = fmaf(f, cs, iz);
        hbuf[tt][c] = o * cs;
    }
    __syncthreads();
    int tt = threadIdx.x & 31;
    int cr = threadIdx.x >> 5;
#pragma unroll
    for (int w = 0; w < 32; w++) {
        int cc = cr + w * 8;
        out[((size_t)(b * CO + cc)) * T_ + ch * CL + tt] = hbuf[tt][cc];
    }
}

extern "C" void kernel_launch(void* const* d_in, const int* in_sizes, int n_in,
                              void* d_out, int out_size, void* d_ws, size_t ws_size,
                              hipStream_t stream) {
    const float* x    = (const float*)d_in[0];
    const float* W    = (const float*)d_in[1];
    const float* bias = (const float*)d_in[2];
    float* out = (float*)d_out;
    float* ws  = (float*)d_ws;

    unsigned short* Xhi = (unsigned short*)(ws + OFF_XHI);
    unsigned short* Xlo = (unsigned short*)(ws + OFF_XLO);
    unsigned short* Whi = (unsigned short*)(ws + OFF_WHI);
    unsigned short* Wlo = (unsigned short*)(ws + OFF_WLO);
    float* fw  = ws + OFF_F;
    float* izw = ws + OFF_IZ;
    float* ow  = ws + OFF_O;
    float* Aw  = ws + OFF_A;
    float* Bw  = ws + OFF_B;
    float* cw  = ws + OFF_C;

    convert_w_kernel<<<(O4 * KK) / 256, 256, 0, stream>>>(W, Whi, Wlo);
    convert_x_kernel<<<dim3(T_ / 64, CIN / 64, B_), 256, 0, stream>>>(x, Xhi, Xlo);
    gemm_mfma_kernel<<<(NN / 128) * (O4 / 128), 256, 0, stream>>>(
        Xhi, Xlo, Whi, Wlo, bias, fw, izw, ow, Aw, Bw);
    scan_phase2<<<B_, CO, 0, stream>>>(Aw, Bw, cw);
    scan_phase3<<<dim3(NCH, B_), CO, 0, stream>>>(fw, izw, ow, cw, out);
}

// Round 4
// 231.518 us; speedup vs baseline: 2.4025x; 1.0983x over previous
//
#include <hip/hip_runtime.h>

#define B_   8
#define CIN  256
#define T_   4096
#define TP   4097    // padded T (row 0 = zeros, row t+1 = x[t])
#define CO   256
#define O4   1024
#define KK   512
#define NN   32768   // B_*T_
#define NCH  128     // chunks along T
#define CL   32      // chunk length

// ws layout (float offsets)
#define OFF_XHI  0           // ushort [8][4097][256]
#define OFF_XLO  4195328
#define OFF_WHI  8390656     // ushort [1024][512]
#define OFF_WLO  8652800
#define OFF_F    8914944     // float [8][4096][256]
#define OFF_IZ   17303552
#define OFF_O    25692160
#define OFF_A    34080768    // float [8][128][256]
#define OFF_B    34342912
#define OFF_C    34605056
// total 34,867,200 floats = 139.5 MB

typedef __attribute__((ext_vector_type(8))) short short8;
typedef __attribute__((ext_vector_type(4))) float floatx4;

__device__ __forceinline__ float fsig(float x)  { return 1.0f / (1.0f + __expf(-x)); }
__device__ __forceinline__ float ftanh(float x) { return 2.0f / (1.0f + __expf(-2.0f * x)) - 1.0f; }

__device__ __forceinline__ unsigned short bf16_rne(float v) {
    unsigned u = __float_as_uint(v);
    unsigned r = (u + 0x7fffu + ((u >> 16) & 1u)) >> 16;
    return (unsigned short)r;
}
__device__ __forceinline__ void split_bf16(float v, unsigned short& hi, unsigned short& lo) {
    hi = bf16_rne(v);
    float hf = __uint_as_float(((unsigned)hi) << 16);
    lo = bf16_rne(v - hf);
}

// async 16B/lane global->LDS DMA; lds base must be wave-uniform (dest = base + lane*16)
__device__ __forceinline__ void glds16(const unsigned short* g, unsigned short* l) {
    __builtin_amdgcn_global_load_lds(
        (const __attribute__((address_space(1))) unsigned*)g,
        (__attribute__((address_space(3))) unsigned*)l, 16, 0, 0);
}

// W[o=g*256+c][i][j] -> Wa[r=c*4+g][k=j*256+i], split hi/lo bf16
__global__ void convert_w_kernel(const float* __restrict__ W,
                                 unsigned short* __restrict__ Whi,
                                 unsigned short* __restrict__ Wlo) {
    int tid = blockIdx.x * 256 + threadIdx.x;   // 1024*512
    int r = tid >> 9, k = tid & 511;
    int g = r & 3, c = r >> 2;
    int j = k >> 8, i = k & 255;
    float v = W[((size_t)((g << 8) + c)) * 512 + i * 2 + j];
    unsigned short hi, lo;
    split_bf16(v, hi, lo);
    Whi[tid] = hi;
    Wlo[tid] = lo;
}

// zero row 0 of each batch in padded X (x[-1] = 0)
__global__ void zero_pad_kernel(unsigned short* __restrict__ Xhi,
                                unsigned short* __restrict__ Xlo) {
    int tid = threadIdx.x;              // 256
    int b = tid >> 5, c0 = (tid & 31) * 8;
    size_t base = (size_t)b * TP * 256 + c0;
#pragma unroll
    for (int j = 0; j < 8; j++) { Xhi[base + j] = 0; Xlo[base + j] = 0; }
}

// x[b][c][t] -> Xpad[b][t+1][c] bf16 hi/lo
__global__ void convert_x_kernel(const float* __restrict__ x,
                                 unsigned short* __restrict__ Xhi,
                                 unsigned short* __restrict__ Xlo) {
    __shared__ float tile[64][65];
    int b  = blockIdx.z;
    int c0 = blockIdx.y * 64;
    int t0 = blockIdx.x * 64;
    int tid = threadIdx.x;

    {   // read coalesced along t
        int j = tid & 63, r4 = tid >> 6;
#pragma unroll
        for (int p = 0; p < 16; p++) {
            int i = p * 4 + r4;
            tile[i][j] = x[((size_t)(b * 256 + c0 + i)) * T_ + t0 + j];
        }
    }
    __syncthreads();
    {   // write coalesced along c
        int i = tid & 63, jj = tid >> 6;
#pragma unroll
        for (int p = 0; p < 16; p++) {
            int t = jj * 16 + p;
            float v = tile[i][t];
            unsigned short hi, lo;
            split_bf16(v, hi, lo);
            size_t idx = ((size_t)b * TP + t0 + t + 1) * 256 + c0 + i;
            Xhi[idx] = hi;
            Xlo[idx] = lo;
        }
    }
}

// C[r=1024][n=32768] = Wa · Xb^T, split-bf16 MFMA (3 products), 128x128 tile, BK=32,
// global_load_lds staging. Epilogue: activations -> LDS [t][c] -> coalesced stores
// + fused per-chunk scan summaries.
__launch_bounds__(256, 3)
__global__ void gemm_mfma_kernel(const unsigned short* __restrict__ Xhi,
                                 const unsigned short* __restrict__ Xlo,
                                 const unsigned short* __restrict__ Whi,
                                 const unsigned short* __restrict__ Wlo,
                                 const float* __restrict__ bias,
                                 float* __restrict__ fw,
                                 float* __restrict__ izw,
                                 float* __restrict__ ow,
                                 float* __restrict__ Aw,
                                 float* __restrict__ Bw)
{
    __shared__ float smem_f[3 * 128 * 33];               // 50,688 B
    unsigned short* smem_us = (unsigned short*)smem_f;
    unsigned short* pA_hi = smem_us;                     // [128][32] contiguous
    unsigned short* pA_lo = smem_us + 4096;
    unsigned short* pB_hi = smem_us + 8192;
    unsigned short* pB_lo = smem_us + 12288;

    const int tid  = threadIdx.x;
    const int wave = tid >> 6, lane = tid & 63;
    const int q = lane >> 4, mr = lane & 15;

    // grid map: XCD(=bid%8) keeps one X-tile for all 8 r-blocks; W L2-resident
    const int bid    = blockIdx.x;
    const int n_sub  = bid & 7;
    const int r_blk  = (bid >> 3) & 7;
    const int n_blk  = (bid >> 6) * 8 + n_sub;
    const int r0 = r_blk * 128;
    const int n0 = n_blk * 128;
    const int bb = n0 >> 12;
    const int t0 = n0 & (T_ - 1);
    const int m_base = (wave & 1) * 64;
    const int n_base = (wave >> 1) * 64;

    // staging: wave w stages rows 32w..32w+31 of each array; 2 DMA instrs/array
    const int lrow = lane >> 2;            // 0..15
    const int lg   = (lane & 3) * 8;       // ushort offset in row
    const size_t wA0 = (size_t)(r0 + wave * 32 + lrow) * 512 + lg;
    const size_t wA1 = wA0 + 16 * 512;
    const size_t xB0 = ((size_t)bb * TP + t0 + wave * 32 + lrow) * 256 + lg;
    const size_t xB1 = xB0 + 16 * 256;
    unsigned short* sAh = pA_hi + wave * 1024;   // wave-uniform LDS bases
    unsigned short* sAl = pA_lo + wave * 1024;
    unsigned short* sBh = pB_hi + wave * 1024;
    unsigned short* sBl = pB_lo + wave * 1024;

    floatx4 acc[4][4];
#pragma unroll
    for (int v = 0; v < 4; v++)
#pragma unroll
        for (int u = 0; u < 4; u++) acc[v][u] = (floatx4){0.f, 0.f, 0.f, 0.f};

    for (int kk = 0; kk < KK; kk += 32) {
        __syncthreads();
        glds16(Whi + wA0 + kk, sAh);
        glds16(Whi + wA1 + kk, sAh + 512);
        glds16(Wlo + wA0 + kk, sAl);
        glds16(Wlo + wA1 + kk, sAl + 512);
        glds16(Xhi + xB0 + kk, sBh);        // tap shift folds into +kk (row+1 at kk=256)
        glds16(Xhi + xB1 + kk, sBh + 512);
        glds16(Xlo + xB0 + kk, sBl);
        glds16(Xlo + xB1 + kk, sBl + 512);
        __syncthreads();

        short8 ah[4], al[4], bh[4], bl[4];
#pragma unroll
        for (int v = 0; v < 4; v++) {
            int m = m_base + v * 16 + mr;
            ah[v] = *(const short8*)(pA_hi + m * 32 + q * 8);
            al[v] = *(const short8*)(pA_lo + m * 32 + q * 8);
        }
#pragma unroll
        for (int u = 0; u < 4; u++) {
            int n = n_base + u * 16 + mr;
            bh[u] = *(const short8*)(pB_hi + n * 32 + q * 8);
            bl[u] = *(const short8*)(pB_lo + n * 32 + q * 8);
        }
#pragma unroll
        for (int v = 0; v < 4; v++)
#pragma unroll
            for (int u = 0; u < 4; u++)
                acc[v][u] = __builtin_amdgcn_mfma_f32_16x16x32_bf16(ah[v], bh[u], acc[v][u], 0, 0, 0);
#pragma unroll
        for (int v = 0; v < 4; v++)
#pragma unroll
            for (int u = 0; u < 4; u++)
                acc[v][u] = __builtin_amdgcn_mfma_f32_16x16x32_bf16(ah[v], bl[u], acc[v][u], 0, 0, 0);
#pragma unroll
        for (int v = 0; v < 4; v++)
#pragma unroll
            for (int u = 0; u < 4; u++)
                acc[v][u] = __builtin_amdgcn_mfma_f32_16x16x32_bf16(al[v], bh[u], acc[v][u], 0, 0, 0);
    }

    // ---------- epilogue ----------
    float* epf = smem_f;                 // [128][33]
    float* epz = smem_f + 4224;
    float* epo = smem_f + 8448;

    __syncthreads();                     // all fragment reads done
#pragma unroll
    for (int v = 0; v < 4; v++) {
        int cl = (m_base >> 2) + v * 4 + q;          // local channel 0..31
        int c  = (r0 >> 2) + cl;
        float bz = bias[c], bf_ = bias[256 + c], bo = bias[512 + c], bi = bias[768 + c];
#pragma unroll
        for (int u = 0; u < 4; u++) {
            int t_l = n_base + u * 16 + mr;
            float zv = ftanh(acc[v][u][0] + bz);
            float fv = fsig (acc[v][u][1] + bf_);
            float ov = fsig (acc[v][u][2] + bo);
            float iv = fsig (acc[v][u][3] + bi);
            int off = t_l * 33 + cl;
            epf[off] = fv;
            epz[off] = iv * zv;
            epo[off] = ov;
        }
    }
    __syncthreads();

    // coalesced stores: thread -> t_r = tid>>1, 16 consecutive c
    {
        const int t_r = tid >> 1;
        const int cb = (tid & 1) << 4;
        const size_t gbase = ((size_t)bb * T_ + t0 + t_r) * 256 + (r0 >> 2) + cb;
        const int lbase = t_r * 33 + cb;
#pragma unroll
        for (int j4 = 0; j4 < 4; j4++) {
            float4 vf = { epf[lbase + j4 * 4], epf[lbase + j4 * 4 + 1],
                          epf[lbase + j4 * 4 + 2], epf[lbase + j4 * 4 + 3] };
            *(float4*)&fw[gbase + j4 * 4] = vf;
        }
#pragma unroll
        for (int j4 = 0; j4 < 4; j4++) {
            float4 vz = { epz[lbase + j4 * 4], epz[lbase + j4 * 4 + 1],
                          epz[lbase + j4 * 4 + 2], epz[lbase + j4 * 4 + 3] };
            *(float4*)&izw[gbase + j4 * 4] = vz;
        }
#pragma unroll
        for (int j4 = 0; j4 < 4; j4++) {
            float4 vo = { epo[lbase + j4 * 4], epo[lbase + j4 * 4 + 1],
                          epo[lbase + j4 * 4 + 2], epo[lbase + j4 * 4 + 3] };
            *(float4*)&ow[gbase + j4 * 4] = vo;
        }
    }

    // fused scan phase 1: per-chunk (A = prod f, B = affine end) from LDS
    if (tid < 128) {
        const int chunk = tid >> 5, cc = tid & 31;
        float A = 1.0f, Bv = 0.0f;
        int base = (chunk * 32) * 33 + cc;
#pragma unroll 4
        for (int j = 0; j < 32; j++) {
            float f  = epf[base + j * 33];
            float iz = epz[base + j * 33];
            Bv = fmaf(f, Bv, iz);
            A *= f;
        }
        const int chunk_abs = (t0 >> 5) + chunk;
        const size_t aidx = ((size_t)bb * NCH + chunk_abs) * 256 + (r0 >> 2) + cc;
        Aw[aidx] = A;
        Bw[aidx] = Bv;
    }
}

// Phase 2: exclusive scan over chunk summaries -> carry-in per chunk
__global__ void scan_phase2(const float* __restrict__ Aw, const float* __restrict__ Bw,
                            float* __restrict__ cw)
{
    int b = blockIdx.x, c = threadIdx.x;
    float carry = 0.0f;
    for (int ch = 0; ch < NCH; ch++) {
        size_t idx = ((size_t)(b * NCH + ch)) * CO + c;
        cw[idx] = carry;
        carry = fmaf(Aw[idx], carry, Bw[idx]);
    }
}

// Phase 3: replay recurrence with carry, h = o*c, transpose [t][c] -> out[b][c][t]
__global__ void scan_phase3(const float* __restrict__ fw, const float* __restrict__ izw,
                            const float* __restrict__ ow, const float* __restrict__ cw,
                            float* __restrict__ out)
{
    __shared__ float hbuf[CL][257];
    int b = blockIdx.y, ch = blockIdx.x, c = threadIdx.x;
    float cs = cw[((size_t)(b * NCH + ch)) * CO + c];
    size_t base = ((size_t)(b * T_ + ch * CL)) * CO + c;
#pragma unroll 4
    for (int tt = 0; tt < CL; tt++) {
        float f  = fw[base + (size_t)tt * CO];
        float iz = izw[base + (size_t)tt * CO];
        float o  = ow[base + (size_t)tt * CO];
        cs = fmaf(f, cs, iz);
        hbuf[tt][c] = o * cs;
    }
    __syncthreads();
    int tt = threadIdx.x & 31;
    int cr = threadIdx.x >> 5;
#pragma unroll
    for (int w = 0; w < 32; w++) {
        int cc = cr + w * 8;
        out[((size_t)(b * CO + cc)) * T_ + ch * CL + tt] = hbuf[tt][cc];
    }
}

extern "C" void kernel_launch(void* const* d_in, const int* in_sizes, int n_in,
                              void* d_out, int out_size, void* d_ws, size_t ws_size,
                              hipStream_t stream) {
    const float* x    = (const float*)d_in[0];
    const float* W    = (const float*)d_in[1];
    const float* bias = (const float*)d_in[2];
    float* out = (float*)d_out;
    float* ws  = (float*)d_ws;

    unsigned short* Xhi = (unsigned short*)(ws + OFF_XHI);
    unsigned short* Xlo = (unsigned short*)(ws + OFF_XLO);
    unsigned short* Whi = (unsigned short*)(ws + OFF_WHI);
    unsigned short* Wlo = (unsigned short*)(ws + OFF_WLO);
    float* fw  = ws + OFF_F;
    float* izw = ws + OFF_IZ;
    float* ow  = ws + OFF_O;
    float* Aw  = ws + OFF_A;
    float* Bw  = ws + OFF_B;
    float* cw  = ws + OFF_C;

    convert_w_kernel<<<(O4 * KK) / 256, 256, 0, stream>>>(W, Whi, Wlo);
    zero_pad_kernel<<<1, 256, 0, stream>>>(Xhi, Xlo);
    convert_x_kernel<<<dim3(T_ / 64, CIN / 64, B_), 256, 0, stream>>>(x, Xhi, Xlo);
    gemm_mfma_kernel<<<(NN / 128) * (O4 / 128), 256, 0, stream>>>(
        Xhi, Xlo, Whi, Wlo, bias, fw, izw, ow, Aw, Bw);
    scan_phase2<<<B_, CO, 0, stream>>>(Aw, Bw, cw);
    scan_phase3<<<dim3(NCH, B_), CO, 0, stream>>>(fw, izw, ow, cw, out);
}